// Round 7
// baseline (416.445 us; speedup 1.0000x reference)
//
#include <hip/hip_runtime.h>
#include <math.h>

// ---------------------------------------------------------------------------
// GCN forward: gcn_norm (self-loops) -> [GEMM + CSR-aggregate + bias + relu] x2
//              -> segment_max pool (fused into agg2 via int atomicMax)
//              -> small FC.
// R5: GEMM1 = split-bf16 MFMA (3 products), absmax 6e-8. Kept.
// R6: aggs reverted to flat U=8 batches (R3 pipeline cost VGPR 32->56,
//     occ 68->36, 68->92us: concurrency-bound, not ILP-bound).
//     agg1 feature-split: 2 waves/node, 64 feats (float1) each ->
//     half the VGPRs, 2x resident waves.
// ---------------------------------------------------------------------------

typedef __attribute__((ext_vector_type(8))) short bfrag;   // 8 bf16 (4 VGPRs)
typedef __attribute__((ext_vector_type(4))) float ffrag;   // MFMA accumulator

__device__ inline void bf16split(float f, short& hi, short& lo) {
    unsigned u = __float_as_uint(f);
    unsigned r = u + 0x7fffu + ((u >> 16) & 1u);            // RNE to bf16
    unsigned short h = (unsigned short)(r >> 16);
    float hf = __uint_as_float(((unsigned)h) << 16);
    float lf = f - hf;
    unsigned ul = __float_as_uint(lf);
    unsigned rl = ul + 0x7fffu + ((ul >> 16) & 1u);
    hi = (short)h;
    lo = (short)(rl >> 16);
}

__global__ __launch_bounds__(256) void k_zero(int* __restrict__ cnt, int* __restrict__ pool,
                                              int n1, int n2) {
    int i = blockIdx.x * 256 + threadIdx.x;
    if (i < n1) cnt[i] = 0;
    if (i < n2) pool[i] = 0;
}

__global__ __launch_bounds__(256) void k_count(const int* __restrict__ ei, int* __restrict__ cnt,
                                               int E) {
    int e = blockIdx.x * 256 + threadIdx.x;
    if (e < E) atomicAdd(&cnt[ei[E + e]], 1);
}

__global__ __launch_bounds__(256) void k_dis(const int* __restrict__ cnt, float* __restrict__ dis,
                                             int N) {
    int v = blockIdx.x * 256 + threadIdx.x;
    if (v < N) dis[v] = 1.0f / sqrtf((float)(cnt[v] + 1));  // +1 self-loop
}

__global__ __launch_bounds__(1024) void k_scan_block(const int* __restrict__ cnt,
                                                     int* __restrict__ rowptr,
                                                     int* __restrict__ bsum, int N) {
    __shared__ int lds[1024];
    int t = threadIdx.x;
    int i = blockIdx.x * 1024 + t;
    int val = (i < N) ? cnt[i] : 0;
    lds[t] = val;
    __syncthreads();
    for (int off = 1; off < 1024; off <<= 1) {
        int u = (t >= off) ? lds[t - off] : 0;
        __syncthreads();
        lds[t] += u;
        __syncthreads();
    }
    if (i < N) rowptr[i] = lds[t] - val;  // exclusive within block
    if (t == 1023) bsum[blockIdx.x] = lds[1023];
}

__global__ __launch_bounds__(1024) void k_scan_tot(const int* __restrict__ bsum,
                                                   int* __restrict__ bsum2, int nb) {
    __shared__ int lds[1024];
    int t = threadIdx.x;
    int val = (t < nb) ? bsum[t] : 0;
    lds[t] = val;
    __syncthreads();
    for (int off = 1; off < 1024; off <<= 1) {
        int u = (t >= off) ? lds[t - off] : 0;
        __syncthreads();
        lds[t] += u;
        __syncthreads();
    }
    if (t < nb) bsum2[t] = lds[t] - val;  // exclusive
}

__global__ __launch_bounds__(256) void k_scan_add(int* __restrict__ rowptr, int* __restrict__ cursor,
                                                  const int* __restrict__ bsum2, int N, int E) {
    int i = blockIdx.x * 256 + threadIdx.x;
    if (i < N) {
        int r = rowptr[i] + bsum2[i >> 10];
        rowptr[i] = r;
        cursor[i] = r;
    }
    if (i == 0) rowptr[N] = E;
}

// packed CSR entry: .x = src index (int bits), .y = edge weight
__global__ __launch_bounds__(256) void k_fill(const int* __restrict__ ei,
                                              const float* __restrict__ dis,
                                              int* __restrict__ cursor,
                                              float2* __restrict__ csr, int E) {
    int e = blockIdx.x * 256 + threadIdx.x;
    if (e >= E) return;
    int r = ei[e];
    int c = ei[E + e];
    int p = atomicAdd(&cursor[c], 1);
    csr[p] = make_float2(__int_as_float(r), dis[r] * dis[c]);
}

// Pre-split W1 (256x128 fp32) into k-major bf16 hi/lo: Wt[col][k] (col=0..127).
__global__ __launch_bounds__(256) void k_wsplit(const float* __restrict__ W,
                                                short* __restrict__ wt_hi,
                                                short* __restrict__ wt_lo) {
    int i = blockIdx.x * 256 + threadIdx.x;
    if (i >= 256 * 128) return;
    int k = i >> 7, c = i & 127;
    short hi, lo;
    bf16split(W[i], hi, lo);
    wt_hi[c * 256 + k] = hi;
    wt_lo[c * 256 + k] = lo;
}

// ---------------------------------------------------------------------------
// GEMM1 via MFMA: C[M x 128] = A[M x 256] @ W1, split-bf16 (3 products).
// ---------------------------------------------------------------------------
__global__ __launch_bounds__(256) void k_gemm1_mfma(const float* __restrict__ A,
                                                    const short* __restrict__ wt_hi,
                                                    const short* __restrict__ wt_lo,
                                                    float* __restrict__ C, int M) {
    constexpr int KD = 256;
    __shared__ short Ah[64][40];
    __shared__ short Al[64][40];

    const int t = threadIdx.x;
    const int lane = t & 63;
    const int wid = t >> 6;      // 0..3
    const int wr = wid >> 1;     // wave row: rows wr*32..+31
    const int wc = wid & 1;      // wave col: cols wc*64..+63
    const int row0 = blockIdx.x * 64;
    const int lrow = lane & 15;
    const int lkg = lane >> 4;

    ffrag acc[2][4];
#pragma unroll
    for (int mr = 0; mr < 2; mr++)
#pragma unroll
        for (int nr = 0; nr < 4; nr++)
#pragma unroll
            for (int q = 0; q < 4; q++) acc[mr][nr][q] = 0.f;

    for (int kc = 0; kc < KD; kc += 32) {
#pragma unroll
        for (int i = 0; i < 2; i++) {
            int s = t * 2 + i;
            int m = s >> 3;           // row in tile
            int kq = s & 7;           // float4 index in k-chunk
            int r = row0 + m;
            float4 v = make_float4(0.f, 0.f, 0.f, 0.f);
            if (r < M) v = *(const float4*)&A[(size_t)r * KD + kc + kq * 4];
            short4 sh, sl;
            bf16split(v.x, sh.x, sl.x);
            bf16split(v.y, sh.y, sl.y);
            bf16split(v.z, sh.z, sl.z);
            bf16split(v.w, sh.w, sl.w);
            *(short4*)&Ah[m][kq * 4] = sh;
            *(short4*)&Al[m][kq * 4] = sl;
        }
        __syncthreads();

        bfrag ahi[2], alo[2];
#pragma unroll
        for (int mr = 0; mr < 2; mr++) {
            int arow = wr * 32 + mr * 16 + lrow;
            ahi[mr] = *(const bfrag*)&Ah[arow][lkg * 8];
            alo[mr] = *(const bfrag*)&Al[arow][lkg * 8];
        }
#pragma unroll
        for (int nr = 0; nr < 4; nr++) {
            int col = wc * 64 + nr * 16 + lrow;
            const size_t boff = (size_t)col * 256 + kc + lkg * 8;
            bfrag bhi = *(const bfrag*)&wt_hi[boff];
            bfrag blo = *(const bfrag*)&wt_lo[boff];
#pragma unroll
            for (int mr = 0; mr < 2; mr++) {
                acc[mr][nr] = __builtin_amdgcn_mfma_f32_16x16x32_bf16(ahi[mr], bhi, acc[mr][nr], 0, 0, 0);
                acc[mr][nr] = __builtin_amdgcn_mfma_f32_16x16x32_bf16(ahi[mr], blo, acc[mr][nr], 0, 0, 0);
                acc[mr][nr] = __builtin_amdgcn_mfma_f32_16x16x32_bf16(alo[mr], bhi, acc[mr][nr], 0, 0, 0);
            }
        }
        __syncthreads();
    }

#pragma unroll
    for (int mr = 0; mr < 2; mr++)
#pragma unroll
        for (int nr = 0; nr < 4; nr++)
#pragma unroll
            for (int q = 0; q < 4; q++) {
                int rr = row0 + wr * 32 + mr * 16 + lkg * 4 + q;
                int cc = wc * 64 + nr * 16 + lrow;
                if (rr < M) C[(size_t)rr * 128 + cc] = acc[mr][nr][q];
            }
}

// ---------------------------------------------------------------------------
// fp32 VALU GEMM (layer 2): C[M x NOUT] = A[M x KDIM] @ W
// ---------------------------------------------------------------------------
template <int KDIM, int NOUT>
__global__ __launch_bounds__(256) void k_gemm(const float* __restrict__ A,
                                              const float* __restrict__ W,
                                              float* __restrict__ C, int M) {
    constexpr int BM = 64, BK = 32;
    constexpr int NGRP = NOUT / 64;
    __shared__ float As[BK][BM + 4];
    __shared__ float Ws[BK][NOUT];

    const int t = threadIdx.x;
    const int tx = t & 15;
    const int ty = t >> 4;
    const int row0 = blockIdx.x * BM;

    float acc[4][4 * NGRP];
#pragma unroll
    for (int r = 0; r < 4; r++)
#pragma unroll
        for (int c = 0; c < 4 * NGRP; c++) acc[r][c] = 0.f;

    for (int kc = 0; kc < KDIM; kc += BK) {
#pragma unroll
        for (int i = 0; i < 2; i++) {
            int s = t * 2 + i;
            int m = s >> 3;
            int kq = s & 7;
            int r = row0 + m;
            float4 v = make_float4(0.f, 0.f, 0.f, 0.f);
            if (r < M) v = *(const float4*)&A[(size_t)r * KDIM + kc + kq * 4];
            As[kq * 4 + 0][m] = v.x;
            As[kq * 4 + 1][m] = v.y;
            As[kq * 4 + 2][m] = v.z;
            As[kq * 4 + 3][m] = v.w;
        }
        constexpr int WLOADS = (BK * NOUT / 4) / 256;
#pragma unroll
        for (int i = 0; i < WLOADS; i++) {
            int s = t + i * 256;
            int k = s / (NOUT / 4);
            int c4 = s % (NOUT / 4);
            *(float4*)&Ws[k][c4 * 4] = *(const float4*)&W[(size_t)(kc + k) * NOUT + c4 * 4];
        }
        __syncthreads();

#pragma unroll
        for (int k = 0; k < BK; k++) {
            float4 a = *(const float4*)&As[k][ty * 4];
            float4 w0 = *(const float4*)&Ws[k][tx * 4];
            float4 w1;
            if (NGRP == 2) w1 = *(const float4*)&Ws[k][64 + tx * 4];
            const float* ap = (const float*)&a;
            const float* w0p = (const float*)&w0;
            const float* w1p = (const float*)&w1;
#pragma unroll
            for (int r = 0; r < 4; r++) {
#pragma unroll
                for (int c = 0; c < 4; c++) {
                    acc[r][c] += ap[r] * w0p[c];
                    if (NGRP == 2) acc[r][4 + c] += ap[r] * w1p[c];
                }
            }
        }
        __syncthreads();
    }

#pragma unroll
    for (int r = 0; r < 4; r++) {
        int rr = row0 + ty * 4 + r;
        if (rr < M) {
            float4 o0 = make_float4(acc[r][0], acc[r][1], acc[r][2], acc[r][3]);
            *(float4*)&C[(size_t)rr * NOUT + tx * 4] = o0;
            if (NGRP == 2) {
                float4 o1 = make_float4(acc[r][4], acc[r][5], acc[r][6], acc[r][7]);
                *(float4*)&C[(size_t)rr * NOUT + 64 + tx * 4] = o1;
            }
        }
    }
}

// Layer-1 aggregate: TWO waves per node, each owns 64 of 128 features
// (1 float/lane). Flat U=8 batch: low VGPR, max resident waves.
__global__ __launch_bounds__(256) void k_agg1(const float* __restrict__ h,
                                              const int* __restrict__ rowptr,
                                              const float2* __restrict__ csr,
                                              const float* __restrict__ dis,
                                              const float* __restrict__ b,
                                              float* __restrict__ out, int N) {
    int wave = (blockIdx.x * 256 + threadIdx.x) >> 6;
    int lane = threadIdx.x & 63;
    int v = wave >> 1;
    int f = ((wave & 1) << 6) + lane;   // feature index 0..127
    if (v >= N) return;
    float d = dis[v];
    float ds2 = d * d;
    float acc = ds2 * h[(size_t)v * 128 + f];
    int s0 = rowptr[v], s1 = rowptr[v + 1];
    for (int j = s0; j < s1; j += 8) {
        int   uu[8];
        float ww[8];
#pragma unroll
        for (int q = 0; q < 8; q++) {
            int jj = j + q;
            bool ok = jj < s1;
            float2 e = csr[ok ? jj : s0];
            uu[q] = ok ? __float_as_int(e.x) : 0;
            ww[q] = ok ? e.y : 0.f;
        }
        float g[8];
#pragma unroll
        for (int q = 0; q < 8; q++) g[q] = h[(size_t)uu[q] * 128 + f];
#pragma unroll
        for (int q = 0; q < 8; q++) acc += ww[q] * g[q];
    }
    out[(size_t)v * 128 + f] = fmaxf(acc + b[f], 0.f);
}

// Layer-2 aggregate: one wave per node, 64 features scalar/lane;
// fused bias+relu+graph max-pool. Flat U=8 batch.
__global__ __launch_bounds__(256) void k_agg2_pool(const float* __restrict__ h,
                                                   const int* __restrict__ rowptr,
                                                   const float2* __restrict__ csr,
                                                   const float* __restrict__ dis,
                                                   const float* __restrict__ b,
                                                   const int* __restrict__ batch,
                                                   float* __restrict__ pool, int N) {
    int wave = (blockIdx.x * 256 + threadIdx.x) >> 6;
    int lane = threadIdx.x & 63;
    if (wave >= N) return;
    const int v = wave;
    float d = dis[v];
    float ds2 = d * d;
    float acc = ds2 * h[(size_t)v * 64 + lane];
    int s0 = rowptr[v], s1 = rowptr[v + 1];
    for (int j = s0; j < s1; j += 8) {
        int   uu[8];
        float ww[8];
#pragma unroll
        for (int q = 0; q < 8; q++) {
            int jj = j + q;
            bool ok = jj < s1;
            float2 e = csr[ok ? jj : s0];
            uu[q] = ok ? __float_as_int(e.x) : 0;
            ww[q] = ok ? e.y : 0.f;
        }
        float g[8];
#pragma unroll
        for (int q = 0; q < 8; q++) g[q] = h[(size_t)uu[q] * 64 + lane];
#pragma unroll
        for (int q = 0; q < 8; q++) acc += ww[q] * g[q];
    }
    float val = fmaxf(acc + b[lane], 0.f);
    int g = batch[v];
    // val >= 0 so float bits order as signed ints; pool zero-initialized.
    atomicMax((int*)&pool[(size_t)g * 64 + lane], __float_as_int(val));
}

__global__ __launch_bounds__(256) void k_fc(const float* __restrict__ pool,
                                            const float* __restrict__ Wfc,
                                            const float* __restrict__ bfc,
                                            float* __restrict__ out, int G) {
    int t = blockIdx.x * 256 + threadIdx.x;
    if (t >= G * 10) return;
    int g = t / 10, o = t % 10;
    float acc = bfc[o];
#pragma unroll
    for (int f = 0; f < 64; f++) acc += pool[g * 64 + f] * Wfc[f * 10 + o];
    out[t] = acc;
}

extern "C" void kernel_launch(void* const* d_in, const int* in_sizes, int n_in,
                              void* d_out, int out_size, void* d_ws, size_t ws_size,
                              hipStream_t stream) {
    const float* x   = (const float*)d_in[0];
    const int*   ei  = (const int*)d_in[1];
    const int*   bat = (const int*)d_in[2];
    const float* W1  = (const float*)d_in[3];
    const float* b1  = (const float*)d_in[4];
    const float* W2  = (const float*)d_in[5];
    const float* b2  = (const float*)d_in[6];
    const float* Wfc = (const float*)d_in[7];
    const float* bfc = (const float*)d_in[8];
    float* out = (float*)d_out;

    const int N = in_sizes[2];          // 50000
    const int E = in_sizes[1] / 2;      // 800000
    const int G = out_size / 10;        // 128

    // workspace layout (256B aligned)
    char* ws = (char*)d_ws;
    size_t off = 0;
    auto alloc = [&](size_t bytes) -> char* {
        char* p = ws + off;
        off = (off + bytes + 255) & ~(size_t)255;
        return p;
    };
    int*    cnt    = (int*)alloc((size_t)N * 4);
    float*  dis    = (float*)alloc((size_t)N * 4);
    int*    rowptr = (int*)alloc((size_t)(N + 1) * 4);
    int*    cursor = (int*)alloc((size_t)N * 4);
    int*    bsum   = (int*)alloc(1024 * 4);
    int*    bsum2  = (int*)alloc(1024 * 4);
    float2* csr    = (float2*)alloc((size_t)E * 8);
    float*  h      = (float*)alloc((size_t)N * 128 * 4);  // h1, reused as h2
    float*  a1     = (float*)alloc((size_t)N * 128 * 4);
    float*  pool   = (float*)alloc((size_t)G * 64 * 4);
    short*  wt_hi  = (short*)alloc(128 * 256 * 2);
    short*  wt_lo  = (short*)alloc(128 * 256 * 2);
    (void)ws_size; (void)n_in;

    const int nb = (N + 1023) / 1024;

    // ---- gcn_norm + CSR build (+ W1 split) ----
    {
        int zmax = N > G * 64 ? N : G * 64;
        k_zero<<<(zmax + 255) / 256, 256, 0, stream>>>(cnt, (int*)pool, N, G * 64);
    }
    k_wsplit<<<128, 256, 0, stream>>>(W1, wt_hi, wt_lo);
    k_count<<<(E + 255) / 256, 256, 0, stream>>>(ei, cnt, E);
    k_dis<<<(N + 255) / 256, 256, 0, stream>>>(cnt, dis, N);
    k_scan_block<<<nb, 1024, 0, stream>>>(cnt, rowptr, bsum, N);
    k_scan_tot<<<1, 1024, 0, stream>>>(bsum, bsum2, nb);
    k_scan_add<<<(N + 255) / 256, 256, 0, stream>>>(rowptr, cursor, bsum2, N, E);
    k_fill<<<(E + 255) / 256, 256, 0, stream>>>(ei, dis, cursor, csr, E);

    // ---- layer 1 (MFMA split-bf16 GEMM; feature-split aggregate) ----
    k_gemm1_mfma<<<(N + 63) / 64, 256, 0, stream>>>(x, wt_hi, wt_lo, h, N);
    {
        long long waves = 2LL * N;
        k_agg1<<<(int)((waves * 64 + 255) / 256), 256, 0, stream>>>(h, rowptr, csr, dis, b1, a1, N);
    }

    // ---- layer 2 (fp32 VALU GEMM; fused aggregate+pool) ----
    k_gemm<128, 64><<<(N + 63) / 64, 256, 0, stream>>>(a1, W2, h, N);
    k_agg2_pool<<<(N * 64 + 255) / 256, 256, 0, stream>>>(h, rowptr, csr, dis, b2, bat, pool, N);

    // ---- FC head ----
    k_fc<<<(G * 10 + 255) / 256, 256, 0, stream>>>(pool, Wfc, bfc, out, G);
}

// Round 8
// 367.049 us; speedup vs baseline: 1.1346x; 1.1346x over previous
//
#include <hip/hip_runtime.h>
#include <math.h>

// ---------------------------------------------------------------------------
// GCN forward: gcn_norm (self-loops) -> [GEMM + CSR-aggregate + bias + relu] x2
//              -> segment_max pool (fused into agg2 via int atomicMax)
//              -> small FC.
// R5: GEMM1 = split-bf16 MFMA (3 products). Kept.
// R6 post-mortem: aggs are L2-miss byte-service bound; 8B/lane single
//     request per edge (R2 shape) is optimal; ILP/occupancy tweaks lose.
// R7: aggs revert to R2 shape; h1/h2 stored as bf16 (gather bytes halved:
//     512->256B and 256->128B per edge; h2 = 6.4MB ~ L2-resident).
// ---------------------------------------------------------------------------

typedef __attribute__((ext_vector_type(8))) short bfrag;   // 8 bf16 (4 VGPRs)
typedef __attribute__((ext_vector_type(4))) float ffrag;   // MFMA accumulator

__device__ inline void bf16split(float f, short& hi, short& lo) {
    unsigned u = __float_as_uint(f);
    unsigned r = u + 0x7fffu + ((u >> 16) & 1u);            // RNE to bf16
    unsigned short h = (unsigned short)(r >> 16);
    float hf = __uint_as_float(((unsigned)h) << 16);
    float lf = f - hf;
    unsigned ul = __float_as_uint(lf);
    unsigned rl = ul + 0x7fffu + ((ul >> 16) & 1u);
    hi = (short)h;
    lo = (short)(rl >> 16);
}

__device__ inline unsigned short f2bf(float f) {
    unsigned u = __float_as_uint(f);
    unsigned r = u + 0x7fffu + ((u >> 16) & 1u);            // RNE
    return (unsigned short)(r >> 16);
}

__global__ __launch_bounds__(256) void k_zero(int* __restrict__ cnt, int* __restrict__ pool,
                                              int n1, int n2) {
    int i = blockIdx.x * 256 + threadIdx.x;
    if (i < n1) cnt[i] = 0;
    if (i < n2) pool[i] = 0;
}

__global__ __launch_bounds__(256) void k_count(const int* __restrict__ ei, int* __restrict__ cnt,
                                               int E) {
    int e = blockIdx.x * 256 + threadIdx.x;
    if (e < E) atomicAdd(&cnt[ei[E + e]], 1);
}

__global__ __launch_bounds__(256) void k_dis(const int* __restrict__ cnt, float* __restrict__ dis,
                                             int N) {
    int v = blockIdx.x * 256 + threadIdx.x;
    if (v < N) dis[v] = 1.0f / sqrtf((float)(cnt[v] + 1));  // +1 self-loop
}

__global__ __launch_bounds__(1024) void k_scan_block(const int* __restrict__ cnt,
                                                     int* __restrict__ rowptr,
                                                     int* __restrict__ bsum, int N) {
    __shared__ int lds[1024];
    int t = threadIdx.x;
    int i = blockIdx.x * 1024 + t;
    int val = (i < N) ? cnt[i] : 0;
    lds[t] = val;
    __syncthreads();
    for (int off = 1; off < 1024; off <<= 1) {
        int u = (t >= off) ? lds[t - off] : 0;
        __syncthreads();
        lds[t] += u;
        __syncthreads();
    }
    if (i < N) rowptr[i] = lds[t] - val;  // exclusive within block
    if (t == 1023) bsum[blockIdx.x] = lds[1023];
}

__global__ __launch_bounds__(1024) void k_scan_tot(const int* __restrict__ bsum,
                                                   int* __restrict__ bsum2, int nb) {
    __shared__ int lds[1024];
    int t = threadIdx.x;
    int val = (t < nb) ? bsum[t] : 0;
    lds[t] = val;
    __syncthreads();
    for (int off = 1; off < 1024; off <<= 1) {
        int u = (t >= off) ? lds[t - off] : 0;
        __syncthreads();
        lds[t] += u;
        __syncthreads();
    }
    if (t < nb) bsum2[t] = lds[t] - val;  // exclusive
}

__global__ __launch_bounds__(256) void k_scan_add(int* __restrict__ rowptr, int* __restrict__ cursor,
                                                  const int* __restrict__ bsum2, int N, int E) {
    int i = blockIdx.x * 256 + threadIdx.x;
    if (i < N) {
        int r = rowptr[i] + bsum2[i >> 10];
        rowptr[i] = r;
        cursor[i] = r;
    }
    if (i == 0) rowptr[N] = E;
}

// packed CSR entry: .x = src index (int bits), .y = edge weight
__global__ __launch_bounds__(256) void k_fill(const int* __restrict__ ei,
                                              const float* __restrict__ dis,
                                              int* __restrict__ cursor,
                                              float2* __restrict__ csr, int E) {
    int e = blockIdx.x * 256 + threadIdx.x;
    if (e >= E) return;
    int r = ei[e];
    int c = ei[E + e];
    int p = atomicAdd(&cursor[c], 1);
    csr[p] = make_float2(__int_as_float(r), dis[r] * dis[c]);
}

// Pre-split W1 (256x128 fp32) into k-major bf16 hi/lo: Wt[col][k] (col=0..127).
__global__ __launch_bounds__(256) void k_wsplit(const float* __restrict__ W,
                                                short* __restrict__ wt_hi,
                                                short* __restrict__ wt_lo) {
    int i = blockIdx.x * 256 + threadIdx.x;
    if (i >= 256 * 128) return;
    int k = i >> 7, c = i & 127;
    short hi, lo;
    bf16split(W[i], hi, lo);
    wt_hi[c * 256 + k] = hi;
    wt_lo[c * 256 + k] = lo;
}

// ---------------------------------------------------------------------------
// GEMM1 via MFMA: h1b[M x 128] (bf16) = A[M x 256] @ W1, split-bf16.
// ---------------------------------------------------------------------------
__global__ __launch_bounds__(256) void k_gemm1_mfma(const float* __restrict__ A,
                                                    const short* __restrict__ wt_hi,
                                                    const short* __restrict__ wt_lo,
                                                    unsigned short* __restrict__ C, int M) {
    constexpr int KD = 256;
    __shared__ short Ah[64][40];
    __shared__ short Al[64][40];

    const int t = threadIdx.x;
    const int lane = t & 63;
    const int wid = t >> 6;      // 0..3
    const int wr = wid >> 1;     // wave row: rows wr*32..+31
    const int wc = wid & 1;      // wave col: cols wc*64..+63
    const int row0 = blockIdx.x * 64;
    const int lrow = lane & 15;
    const int lkg = lane >> 4;

    ffrag acc[2][4];
#pragma unroll
    for (int mr = 0; mr < 2; mr++)
#pragma unroll
        for (int nr = 0; nr < 4; nr++)
#pragma unroll
            for (int q = 0; q < 4; q++) acc[mr][nr][q] = 0.f;

    for (int kc = 0; kc < KD; kc += 32) {
#pragma unroll
        for (int i = 0; i < 2; i++) {
            int s = t * 2 + i;
            int m = s >> 3;           // row in tile
            int kq = s & 7;           // float4 index in k-chunk
            int r = row0 + m;
            float4 v = make_float4(0.f, 0.f, 0.f, 0.f);
            if (r < M) v = *(const float4*)&A[(size_t)r * KD + kc + kq * 4];
            short4 sh, sl;
            bf16split(v.x, sh.x, sl.x);
            bf16split(v.y, sh.y, sl.y);
            bf16split(v.z, sh.z, sl.z);
            bf16split(v.w, sh.w, sl.w);
            *(short4*)&Ah[m][kq * 4] = sh;
            *(short4*)&Al[m][kq * 4] = sl;
        }
        __syncthreads();

        bfrag ahi[2], alo[2];
#pragma unroll
        for (int mr = 0; mr < 2; mr++) {
            int arow = wr * 32 + mr * 16 + lrow;
            ahi[mr] = *(const bfrag*)&Ah[arow][lkg * 8];
            alo[mr] = *(const bfrag*)&Al[arow][lkg * 8];
        }
#pragma unroll
        for (int nr = 0; nr < 4; nr++) {
            int col = wc * 64 + nr * 16 + lrow;
            const size_t boff = (size_t)col * 256 + kc + lkg * 8;
            bfrag bhi = *(const bfrag*)&wt_hi[boff];
            bfrag blo = *(const bfrag*)&wt_lo[boff];
#pragma unroll
            for (int mr = 0; mr < 2; mr++) {
                acc[mr][nr] = __builtin_amdgcn_mfma_f32_16x16x32_bf16(ahi[mr], bhi, acc[mr][nr], 0, 0, 0);
                acc[mr][nr] = __builtin_amdgcn_mfma_f32_16x16x32_bf16(ahi[mr], blo, acc[mr][nr], 0, 0, 0);
                acc[mr][nr] = __builtin_amdgcn_mfma_f32_16x16x32_bf16(alo[mr], bhi, acc[mr][nr], 0, 0, 0);
            }
        }
        __syncthreads();
    }

#pragma unroll
    for (int mr = 0; mr < 2; mr++)
#pragma unroll
        for (int nr = 0; nr < 4; nr++)
#pragma unroll
            for (int q = 0; q < 4; q++) {
                int rr = row0 + wr * 32 + mr * 16 + lkg * 4 + q;
                int cc = wc * 64 + nr * 16 + lrow;
                if (rr < M) C[(size_t)rr * 128 + cc] = f2bf(acc[mr][nr][q]);
            }
}

// ---------------------------------------------------------------------------
// fp32 VALU GEMM (layer 2), bf16 output: h2b[M x 64] = a1[M x 128] @ W2
// ---------------------------------------------------------------------------
__global__ __launch_bounds__(256) void k_gemm2(const float* __restrict__ A,
                                               const float* __restrict__ W,
                                               unsigned short* __restrict__ C, int M) {
    constexpr int KDIM = 128, NOUT = 64, BM = 64, BK = 32;
    __shared__ float As[BK][BM + 4];
    __shared__ float Ws[BK][NOUT];

    const int t = threadIdx.x;
    const int tx = t & 15;
    const int ty = t >> 4;
    const int row0 = blockIdx.x * BM;

    float acc[4][4];
#pragma unroll
    for (int r = 0; r < 4; r++)
#pragma unroll
        for (int c = 0; c < 4; c++) acc[r][c] = 0.f;

    for (int kc = 0; kc < KDIM; kc += BK) {
#pragma unroll
        for (int i = 0; i < 2; i++) {
            int s = t * 2 + i;
            int m = s >> 3;
            int kq = s & 7;
            int r = row0 + m;
            float4 v = make_float4(0.f, 0.f, 0.f, 0.f);
            if (r < M) v = *(const float4*)&A[(size_t)r * KDIM + kc + kq * 4];
            As[kq * 4 + 0][m] = v.x;
            As[kq * 4 + 1][m] = v.y;
            As[kq * 4 + 2][m] = v.z;
            As[kq * 4 + 3][m] = v.w;
        }
        // W tile: 32 x 64 floats = 512 float4, 2/thread
#pragma unroll
        for (int i = 0; i < 2; i++) {
            int s = t + i * 256;
            int k = s / 16;
            int c4 = s % 16;
            *(float4*)&Ws[k][c4 * 4] = *(const float4*)&W[(size_t)(kc + k) * NOUT + c4 * 4];
        }
        __syncthreads();

#pragma unroll
        for (int k = 0; k < BK; k++) {
            float4 a = *(const float4*)&As[k][ty * 4];
            float4 w0 = *(const float4*)&Ws[k][tx * 4];
            const float* ap = (const float*)&a;
            const float* w0p = (const float*)&w0;
#pragma unroll
            for (int r = 0; r < 4; r++)
#pragma unroll
                for (int c = 0; c < 4; c++) acc[r][c] += ap[r] * w0p[c];
        }
        __syncthreads();
    }

#pragma unroll
    for (int r = 0; r < 4; r++) {
        int rr = row0 + ty * 4 + r;
        if (rr < M) {
            ushort4 o;
            o.x = f2bf(acc[r][0]);
            o.y = f2bf(acc[r][1]);
            o.z = f2bf(acc[r][2]);
            o.w = f2bf(acc[r][3]);
            *(ushort4*)&C[(size_t)rr * NOUT + tx * 4] = o;
        }
    }
}

// Layer-1 aggregate: one wave/node, 128 bf16 feats as one uint (2 feats)/lane.
// Flat U=8 batch (R2 shape). out = relu(agg + b), fp32.
__global__ __launch_bounds__(256) void k_agg1(const unsigned int* __restrict__ h1b,
                                              const int* __restrict__ rowptr,
                                              const float2* __restrict__ csr,
                                              const float* __restrict__ dis,
                                              const float* __restrict__ b,
                                              float* __restrict__ out, int N) {
    int wave = (blockIdx.x * 256 + threadIdx.x) >> 6;
    int lane = threadIdx.x & 63;
    if (wave >= N) return;
    const int v = wave;
    float d = dis[v];
    float ds2 = d * d;
    unsigned hv = h1b[(size_t)v * 64 + lane];
    float ax = ds2 * __uint_as_float(hv << 16);           // feat 2*lane
    float ay = ds2 * __uint_as_float(hv & 0xffff0000u);   // feat 2*lane+1
    int s0 = rowptr[v], s1 = rowptr[v + 1];
    for (int j = s0; j < s1; j += 8) {
        int   uu[8];
        float ww[8];
#pragma unroll
        for (int q = 0; q < 8; q++) {
            int jj = j + q;
            bool ok = jj < s1;
            float2 e = csr[ok ? jj : s0];
            uu[q] = ok ? __float_as_int(e.x) : 0;
            ww[q] = ok ? e.y : 0.f;
        }
        unsigned g[8];
#pragma unroll
        for (int q = 0; q < 8; q++) g[q] = h1b[(size_t)uu[q] * 64 + lane];
#pragma unroll
        for (int q = 0; q < 8; q++) {
            ax += ww[q] * __uint_as_float(g[q] << 16);
            ay += ww[q] * __uint_as_float(g[q] & 0xffff0000u);
        }
    }
    float2 bb = *(const float2*)&b[lane * 2];
    float2 o;
    o.x = fmaxf(ax + bb.x, 0.f);
    o.y = fmaxf(ay + bb.y, 0.f);
    *(float2*)&out[(size_t)v * 128 + lane * 2] = o;
}

// Layer-2 aggregate: one wave/node, 64 bf16 feats (1 ushort/lane);
// fused bias+relu+graph max-pool. Flat U=8 batch.
__global__ __launch_bounds__(256) void k_agg2_pool(const unsigned short* __restrict__ h2b,
                                                   const int* __restrict__ rowptr,
                                                   const float2* __restrict__ csr,
                                                   const float* __restrict__ dis,
                                                   const float* __restrict__ b,
                                                   const int* __restrict__ batch,
                                                   float* __restrict__ pool, int N) {
    int wave = (blockIdx.x * 256 + threadIdx.x) >> 6;
    int lane = threadIdx.x & 63;
    if (wave >= N) return;
    const int v = wave;
    float d = dis[v];
    float ds2 = d * d;
    float acc = ds2 * __uint_as_float(((unsigned)h2b[(size_t)v * 64 + lane]) << 16);
    int s0 = rowptr[v], s1 = rowptr[v + 1];
    for (int j = s0; j < s1; j += 8) {
        int   uu[8];
        float ww[8];
#pragma unroll
        for (int q = 0; q < 8; q++) {
            int jj = j + q;
            bool ok = jj < s1;
            float2 e = csr[ok ? jj : s0];
            uu[q] = ok ? __float_as_int(e.x) : 0;
            ww[q] = ok ? e.y : 0.f;
        }
        unsigned short g[8];
#pragma unroll
        for (int q = 0; q < 8; q++) g[q] = h2b[(size_t)uu[q] * 64 + lane];
#pragma unroll
        for (int q = 0; q < 8; q++) acc += ww[q] * __uint_as_float(((unsigned)g[q]) << 16);
    }
    float val = fmaxf(acc + b[lane], 0.f);
    int g = batch[v];
    // val >= 0 so float bits order as signed ints; pool zero-initialized.
    atomicMax((int*)&pool[(size_t)g * 64 + lane], __float_as_int(val));
}

__global__ __launch_bounds__(256) void k_fc(const float* __restrict__ pool,
                                            const float* __restrict__ Wfc,
                                            const float* __restrict__ bfc,
                                            float* __restrict__ out, int G) {
    int t = blockIdx.x * 256 + threadIdx.x;
    if (t >= G * 10) return;
    int g = t / 10, o = t % 10;
    float acc = bfc[o];
#pragma unroll
    for (int f = 0; f < 64; f++) acc += pool[g * 64 + f] * Wfc[f * 10 + o];
    out[t] = acc;
}

extern "C" void kernel_launch(void* const* d_in, const int* in_sizes, int n_in,
                              void* d_out, int out_size, void* d_ws, size_t ws_size,
                              hipStream_t stream) {
    const float* x   = (const float*)d_in[0];
    const int*   ei  = (const int*)d_in[1];
    const int*   bat = (const int*)d_in[2];
    const float* W1  = (const float*)d_in[3];
    const float* b1  = (const float*)d_in[4];
    const float* W2  = (const float*)d_in[5];
    const float* b2  = (const float*)d_in[6];
    const float* Wfc = (const float*)d_in[7];
    const float* bfc = (const float*)d_in[8];
    float* out = (float*)d_out;

    const int N = in_sizes[2];          // 50000
    const int E = in_sizes[1] / 2;      // 800000
    const int G = out_size / 10;        // 128

    // workspace layout (256B aligned)
    char* ws = (char*)d_ws;
    size_t off = 0;
    auto alloc = [&](size_t bytes) -> char* {
        char* p = ws + off;
        off = (off + bytes + 255) & ~(size_t)255;
        return p;
    };
    int*    cnt    = (int*)alloc((size_t)N * 4);
    float*  dis    = (float*)alloc((size_t)N * 4);
    int*    rowptr = (int*)alloc((size_t)(N + 1) * 4);
    int*    cursor = (int*)alloc((size_t)N * 4);
    int*    bsum   = (int*)alloc(1024 * 4);
    int*    bsum2  = (int*)alloc(1024 * 4);
    float2* csr    = (float2*)alloc((size_t)E * 8);
    unsigned short* h1b = (unsigned short*)alloc((size_t)N * 128 * 2);
    float*  a1     = (float*)alloc((size_t)N * 128 * 4);
    unsigned short* h2b = (unsigned short*)alloc((size_t)N * 64 * 2);
    float*  pool   = (float*)alloc((size_t)G * 64 * 4);
    short*  wt_hi  = (short*)alloc(128 * 256 * 2);
    short*  wt_lo  = (short*)alloc(128 * 256 * 2);
    (void)ws_size; (void)n_in;

    const int nb = (N + 1023) / 1024;

    // ---- gcn_norm + CSR build (+ W1 split) ----
    {
        int zmax = N > G * 64 ? N : G * 64;
        k_zero<<<(zmax + 255) / 256, 256, 0, stream>>>(cnt, (int*)pool, N, G * 64);
    }
    k_wsplit<<<128, 256, 0, stream>>>(W1, wt_hi, wt_lo);
    k_count<<<(E + 255) / 256, 256, 0, stream>>>(ei, cnt, E);
    k_dis<<<(N + 255) / 256, 256, 0, stream>>>(cnt, dis, N);
    k_scan_block<<<nb, 1024, 0, stream>>>(cnt, rowptr, bsum, N);
    k_scan_tot<<<1, 1024, 0, stream>>>(bsum, bsum2, nb);
    k_scan_add<<<(N + 255) / 256, 256, 0, stream>>>(rowptr, cursor, bsum2, N, E);
    k_fill<<<(E + 255) / 256, 256, 0, stream>>>(ei, dis, cursor, csr, E);

    // ---- layer 1 (MFMA split-bf16 GEMM -> bf16 h1; bf16 gathers) ----
    k_gemm1_mfma<<<(N + 63) / 64, 256, 0, stream>>>(x, wt_hi, wt_lo, h1b, N);
    k_agg1<<<(N * 64 + 255) / 256, 256, 0, stream>>>((const unsigned int*)h1b, rowptr, csr,
                                                     dis, b1, a1, N);

    // ---- layer 2 (fp32 GEMM -> bf16 h2; bf16 gathers; fused pool) ----
    k_gemm2<<<(N + 63) / 64, 256, 0, stream>>>(a1, W2, h2b, N);
    k_agg2_pool<<<(N * 64 + 255) / 256, 256, 0, stream>>>(h2b, rowptr, csr, dis, b2, bat,
                                                          pool, N);

    // ---- FC head ----
    k_fc<<<(G * 10 + 255) / 256, 256, 0, stream>>>(pool, Wfc, bfc, out, G);
}